// Round 14
// baseline (447.931 us; speedup 1.0000x reference)
//
#include <hip/hip_runtime.h>
#include <stdint.h>

#define B_ 4096
#define D_ 768
#define F_ 16384
#define M_ 256

typedef short bf16x8 __attribute__((ext_vector_type(8)));
typedef float f32x4 __attribute__((ext_vector_type(4)));
typedef unsigned short ushort8 __attribute__((ext_vector_type(8)));

__device__ __forceinline__ unsigned short f2bf(float f) {
  union { float f; uint32_t u; } c; c.f = f;
  uint32_t u = c.u;
  uint32_t r = (u + 0x7FFFu + ((u >> 16) & 1u)) >> 16;
  return (unsigned short)r;
}

__device__ __forceinline__ float bf2f(unsigned short s) {
  union { uint32_t u; float f; } c; c.u = ((uint32_t)s) << 16;
  return c.f;
}

__device__ __forceinline__ void gl_lds16(const void* g, void* l) {
  __builtin_amdgcn_global_load_lds(
      (const __attribute__((address_space(1))) unsigned int*)g,
      (__attribute__((address_space(3))) unsigned int*)l, 16, 0, 0);
}

// ---------------- fused f32 -> bf16 casts for all 5 inputs (one launch) ------------
__global__ void cast_all(const float* __restrict__ x, const float* __restrict__ mb,
                         const float* __restrict__ Wq, const float* __restrict__ Wk,
                         const float* __restrict__ Wv,
                         unsigned short* __restrict__ xb, unsigned short* __restrict__ mbb,
                         unsigned short* __restrict__ Wqb, unsigned short* __restrict__ Wkb,
                         unsigned short* __restrict__ Wvb, float* __restrict__ out_x) {
  int i = blockIdx.x * blockDim.x + threadIdx.x;  // float4 units
  const int NX = B_ * D_ / 4;    // 786432
  const int NMB = F_ * D_ / 4;   // 3145728
  const int NW = M_ * D_ / 4;    // 49152
  const int NWV = D_ * D_ / 4;   // 147456
  const float* src;
  unsigned short* dst;
  float* cpy = nullptr;
  int off;
  if (i < NX) { src = x; dst = xb; off = i; cpy = out_x; }
  else if ((i -= NX) < NMB) { src = mb; dst = mbb; off = i; }
  else if ((i -= NMB) < NW) { src = Wq; dst = Wqb; off = i; }
  else if ((i -= NW) < NW) { src = Wk; dst = Wkb; off = i; }
  else if ((i -= NW) < NWV) { src = Wv; dst = Wvb; off = i; }
  else return;
  float4 v = reinterpret_cast<const float4*>(src)[off];
  ushort4 u;
  u.x = f2bf(v.x); u.y = f2bf(v.y); u.z = f2bf(v.z); u.w = f2bf(v.w);
  reinterpret_cast<ushort4*>(dst)[off] = u;
  if (cpy) reinterpret_cast<float4*>(cpy)[off] = v;
}
#define CAST_UNITS (B_ * D_ / 4 + F_ * D_ / 4 + 2 * (M_ * D_ / 4) + D_ * D_ / 4)

// ---------------- gemm_bt: C[M,N] = A[M,K] * B[N,K]^T  (both bf16 K-contiguous) ----
// EPI 0: store bf16 (+bias)   EPI 1: store f32 (+bias)
// EPI 2: exp(c/temp) -> f32 E + rowsum      (fallback path)
// EPI 3: exp(c/temp) -> bf16 TILED E via LDS restage (coalesced ushort8) + rowsum
template <int EPI>
__global__ __launch_bounds__(256, 2) void gemm_bt(
    const unsigned short* __restrict__ A, const unsigned short* __restrict__ Bm,
    const float* __restrict__ bias, float* __restrict__ Cf,
    unsigned short* __restrict__ Cb, int M, int N, int K,
    float* __restrict__ rowsum, const float* __restrict__ tptr) {
  __shared__ unsigned short As[128 * 32];
  __shared__ unsigned short Bs[128 * 32];
  const int tid = threadIdx.x, lane = tid & 63, wave = tid >> 6;
  const int m0 = blockIdx.y * 128, n0 = blockIdx.x * 128;
  const int wr = wave >> 1, wc = wave & 1;
  const int q = lane >> 4;
  f32x4 acc[4][4] = {};

  for (int k0 = 0; k0 < K; k0 += 32) {
#pragma unroll
    for (int i = 0; i < 2; ++i) {
      int cb = (i * 4 + wave) * 64;
      int ch = cb + lane;
      int row = ch >> 2, ko = (ch & 3) * 8;
      gl_lds16(A + (size_t)(m0 + row) * K + k0 + ko, (char*)As + (size_t)cb * 16);
      gl_lds16(Bm + (size_t)(n0 + row) * K + k0 + ko, (char*)Bs + (size_t)cb * 16);
    }
    __syncthreads();
    bf16x8 a[4];
#pragma unroll
    for (int m = 0; m < 4; ++m)
      a[m] = *reinterpret_cast<const bf16x8*>(
          &As[(wr * 64 + m * 16 + (lane & 15)) * 32 + q * 8]);
#pragma unroll
    for (int n = 0; n < 4; ++n) {
      bf16x8 b = *reinterpret_cast<const bf16x8*>(
          &Bs[(wc * 64 + n * 16 + (lane & 15)) * 32 + q * 8]);
#pragma unroll
      for (int m = 0; m < 4; ++m)
        acc[m][n] = __builtin_amdgcn_mfma_f32_16x16x32_bf16(a[m], b, acc[m][n], 0, 0, 0);
    }
    __syncthreads();
  }

  const int rbase = m0 + wr * 64 + q * 4;
  const int cbase = n0 + wc * 64 + (lane & 15);
  if constexpr (EPI == 3) {
    __shared__ unsigned short Cs[128 * 128];   // 32 KB restage tile
    const float invt = 1.0f / tptr[0];
    const int rl0 = wr * 64 + q * 4, cl0 = wc * 64 + (lane & 15);
#pragma unroll
    for (int m = 0; m < 4; ++m) {
      float rs[4] = {0.f, 0.f, 0.f, 0.f};
#pragma unroll
      for (int n = 0; n < 4; ++n) {
#pragma unroll
        for (int r = 0; r < 4; ++r) {
          float e = __expf(acc[m][n][r] * invt);
          rs[r] += e;
          Cs[(rl0 + m * 16 + r) * 128 + cl0 + n * 16] = f2bf(e);
        }
      }
#pragma unroll
      for (int r = 0; r < 4; ++r) {
        float s = rs[r];
        s += __shfl_xor(s, 1);
        s += __shfl_xor(s, 2);
        s += __shfl_xor(s, 4);
        s += __shfl_xor(s, 8);
        if ((lane & 15) == 0) atomicAdd(&rowsum[rbase + m * 16 + r], s);
      }
    }
    __syncthreads();
    // coalesced tiled-E writeout: 2048 ushort8 units, 8 per thread
    const size_t ebase = ((size_t)(m0 >> 7) * 512 + (n0 >> 5)) * 4096;
#pragma unroll
    for (int j = 0; j < 8; ++j) {
      int u = j * 256 + tid;
      int tl = u >> 9, r = (u >> 2) & 127, p = u & 3;
      ushort8 v = *reinterpret_cast<const ushort8*>(
          &Cs[r * 128 + tl * 32 + ((p ^ ((r >> 1) & 3)) * 8)]);
      *reinterpret_cast<ushort8*>(&Cb[ebase + (size_t)tl * 4096 + r * 32 + p * 8]) = v;
    }
  } else if constexpr (EPI == 2) {
    const float invt = 1.0f / tptr[0];
#pragma unroll
    for (int m = 0; m < 4; ++m) {
      float rs[4] = {0.f, 0.f, 0.f, 0.f};
#pragma unroll
      for (int n = 0; n < 4; ++n) {
        int col = cbase + n * 16;
#pragma unroll
        for (int r = 0; r < 4; ++r) {
          float e = __expf(acc[m][n][r] * invt);
          Cf[(size_t)(rbase + m * 16 + r) * N + col] = e;
          rs[r] += e;
        }
      }
#pragma unroll
      for (int r = 0; r < 4; ++r) {
        float s = rs[r];
        s += __shfl_xor(s, 1);
        s += __shfl_xor(s, 2);
        s += __shfl_xor(s, 4);
        s += __shfl_xor(s, 8);
        if ((lane & 15) == 0) atomicAdd(&rowsum[rbase + m * 16 + r], s);
      }
    }
  } else {
#pragma unroll
    for (int m = 0; m < 4; ++m) {
#pragma unroll
      for (int n = 0; n < 4; ++n) {
        int col = cbase + n * 16;
        float bv = bias[col];
#pragma unroll
        for (int r = 0; r < 4; ++r) {
          float v = acc[m][n][r] + bv;
          size_t idx = (size_t)(rbase + m * 16 + r) * N + col;
          if (EPI == 0) Cb[idx] = f2bf(v);
          else Cf[idx] = v;
        }
      }
    }
  }
}

// ---------------- V[16384,768] f32 -> Vt_tiled bf16 --------------------------------
// Tile t: 48KB contiguous; xhat LDS image with XOR slot-swizzle pre-applied:
//   Vt_tiled[t*24576 + d*32 + s*8 + o] = bf16( V[t*32 + (s^((d>>1)&3))*8 + o][d] )
__global__ __launch_bounds__(256) void vt_tiler(const float* __restrict__ V,
                                                unsigned short* __restrict__ Vt_tiled) {
  __shared__ unsigned short T[768][36];
  const int t = blockIdx.x, k0 = t * 32, tid = threadIdx.x;
  const int kl = tid >> 3, c0 = (tid & 7) * 4;
  for (int cb = 0; cb < 768; cb += 32) {
    float4 v = *reinterpret_cast<const float4*>(&V[(size_t)(k0 + kl) * D_ + cb + c0]);
    T[cb + c0 + 0][kl] = f2bf(v.x);
    T[cb + c0 + 1][kl] = f2bf(v.y);
    T[cb + c0 + 2][kl] = f2bf(v.z);
    T[cb + c0 + 3][kl] = f2bf(v.w);
  }
  __syncthreads();
  for (int d = tid; d < 768; d += 256) {
    const int x = (d >> 1) & 3;
    unsigned short* o = Vt_tiled + (size_t)t * 24576 + d * 32;
#pragma unroll
    for (int s = 0; s < 4; ++s) {
      ushort4 lo = *reinterpret_cast<const ushort4*>(&T[d][(s ^ x) * 8]);
      ushort4 hi = *reinterpret_cast<const ushort4*>(&T[d][(s ^ x) * 8 + 4]);
      *reinterpret_cast<ushort4*>(o + s * 8) = lo;
      *reinterpret_cast<ushort4*>(o + s * 8 + 4) = hi;
    }
  }
}

// ---------------- xhat (r8-proven loop, KS=8 grid for 4 blocks/CU) -----------------
// partial[ks][128x192 tile] = (E_chunk @ V_chunk) * diag(1/rowsum), bf16.
// Wave grid 2x4, wave tile 64x48, acc[4][3]. Waves 0-3 stage A (4 chunks each = 16),
// waves 4-7 stage B (6 chunks each = 24 = 192rows x 64k). 32 steps, 48 MFMA/wave.
// combo = bid&31 (ks=combo>>2 in 0..7, nb=combo&3), mb = bid>>5. Grid 1024 = 4
// blocks/CU (LDS 40KB x4 = 160KB, VGPR 64 -> 8 waves/SIMD). bid%8 = combo%8 pins
// each XCD to 4 (ks, fixed-nb) V-panels = 4 x 0.75MB = 3MB < 4MB L2.
__global__ __launch_bounds__(512, 4) void xhat_clean(
    const unsigned short* __restrict__ Et, const unsigned short* __restrict__ Vtt,
    const float* __restrict__ rowsum, unsigned short* __restrict__ partial) {
  __shared__ unsigned short As[2][128 * 32];   // 16 KB
  __shared__ unsigned short Bs[2][192 * 32];   // 24 KB
  const int tid = threadIdx.x, lane = tid & 63, wave = tid >> 6;
  const int combo = blockIdx.x & 31, mb = blockIdx.x >> 5;
  const int ks = combo >> 2, nb = combo & 3;
  const int q = lane >> 4;
  const int wr = wave >> 2, wc = wave & 3;  // wave tile 64r x 48c
  const int t0 = ks * 64;                   // 64 k-tiles (2048 k) per chunk
  f32x4 acc[4][3] = {};

  const unsigned short* abase =
      Et + ((size_t)mb * 512 + t0) * 4096 + lane * 8;
  const unsigned short* bbase =
      Vtt + (size_t)t0 * 24576 + nb * 6144 + lane * 8;

  for (int si = 0; si < 32; ++si) {
    const size_t tA = (size_t)(2 * si) * 4096;
    const size_t tB = (size_t)(2 * si) * 24576;
    if (wave < 4) {
      // A: 128r x 64k = 16 chunks of 512 shorts; 4 per wave
#pragma unroll
      for (int j = 0; j < 4; ++j) {
        int c = wave * 4 + j;         // 0..15
        int h = c >> 3, cw = c & 7;
        gl_lds16(abase + tA + (size_t)h * 4096 + cw * 512,
                 (char*)As + h * 8192 + cw * 1024);
      }
    } else {
      // B: 192r x 64k = 24 chunks of 512 shorts; 6 per wave
#pragma unroll
      for (int j = 0; j < 6; ++j) {
        int c = (wave - 4) * 6 + j;   // 0..23
        int h = c / 12, cc = c % 12;
        gl_lds16(bbase + tB + (size_t)h * 24576 + cc * 512,
                 (char*)Bs + h * 12288 + cc * 1024);
      }
    }
    __syncthreads();
#pragma unroll
    for (int h = 0; h < 2; ++h) {
      bf16x8 a[4], b[3];
#pragma unroll
      for (int m = 0; m < 4; ++m) {
        int R = wr * 64 + m * 16 + (lane & 15);
        a[m] = *reinterpret_cast<const bf16x8*>(
            &As[h][R * 32 + ((q ^ ((R >> 1) & 3)) * 8)]);
      }
#pragma unroll
      for (int n = 0; n < 3; ++n) {
        int C = wc * 48 + n * 16 + (lane & 15);
        b[n] = *reinterpret_cast<const bf16x8*>(
            &Bs[h][C * 32 + ((q ^ ((C >> 1) & 3)) * 8)]);
      }
#pragma unroll
      for (int n = 0; n < 3; ++n)
#pragma unroll
        for (int m = 0; m < 4; ++m)
          acc[m][n] = __builtin_amdgcn_mfma_f32_16x16x32_bf16(a[m], b[n], acc[m][n], 0, 0, 0);
    }
    __syncthreads();
  }

  unsigned short* P = partial + (size_t)ks * B_ * D_;
#pragma unroll
  for (int m = 0; m < 4; ++m) {
    int rowb = mb * 128 + wr * 64 + m * 16 + q * 4;
#pragma unroll
    for (int r = 0; r < 4; ++r) {
      float inv = 1.0f / rowsum[rowb + r];
      size_t ro = (size_t)(rowb + r) * D_;
#pragma unroll
      for (int n = 0; n < 3; ++n) {
        int col = nb * 192 + wc * 48 + n * 16 + (lane & 15);
        P[ro + col] = f2bf(acc[m][n][r] * inv);
      }
    }
  }
}

// ---------------- f[row][col] = bf2f(E_tiled)*inv_rs  (streaming, coalesced) -------
__global__ __launch_bounds__(256) void normalize_f(
    const unsigned short* __restrict__ Et, const float* __restrict__ rowsum,
    float* __restrict__ f) {
  int u = blockIdx.x * blockDim.x + threadIdx.x;  // one unit = 8 shorts
  int g = u >> 9, w = u & 511;                    // 512 units per 128x32 tile
  int r = w >> 2, p = w & 3;
  int rb = g >> 9, t = g & 511;
  int row = rb * 128 + r;
  int col = t * 32 + (p ^ ((r >> 1) & 3)) * 8;
  float inv = 1.0f / rowsum[row];
  ushort8 e = *reinterpret_cast<const ushort8*>(&Et[(size_t)g * 4096 + w * 8]);
  float4 o0, o1;
  o0.x = bf2f(e[0]) * inv; o0.y = bf2f(e[1]) * inv;
  o0.z = bf2f(e[2]) * inv; o0.w = bf2f(e[3]) * inv;
  o1.x = bf2f(e[4]) * inv; o1.y = bf2f(e[5]) * inv;
  o1.z = bf2f(e[6]) * inv; o1.w = bf2f(e[7]) * inv;
  float* fp = &f[(size_t)row * F_ + col];
  *reinterpret_cast<float4*>(fp) = o0;
  *reinterpret_cast<float4*>(fp + 4) = o1;
}

// ---------------- xhat v4 (fallback, round-4 proven) -------------------------------
__global__ __launch_bounds__(512, 4) void xhat_v4(
    float* __restrict__ Ef, const unsigned short* __restrict__ Vt_tiled,
    const float* __restrict__ rowsum, unsigned short* __restrict__ partial) {
  __shared__ unsigned short As2[64 * 32];
  __shared__ unsigned short Vs[768 * 32];
  const int tid = threadIdx.x, lane = tid & 63, wave = tid >> 6;
  const int ks = blockIdx.x & 7, rb = blockIdx.x >> 3;
  const int r0 = rb * 64;
  const int kbeg = ks * (F_ / 8);
  const int wr = wave >> 2, wc = wave & 3;
  const int erow = tid >> 3, ec = (tid & 7) * 4;
  const float inv_f = 1.0f / rowsum[r0 + erow];
  const int q = lane >> 4;
  f32x4 acc[2][12] = {};

  float* ep = Ef + (size_t)(r0 + erow) * F_ + kbeg + ec;
  float4 e = *reinterpret_cast<const float4*>(ep);
  const int NSTEP = (F_ / 8) / 32;
  const unsigned short* vt_base =
      Vt_tiled + (size_t)(kbeg >> 5) * 24576 + wave * 512 + lane * 8;

  for (int si = 0; si < NSTEP; ++si) {
    float4 f4 = make_float4(e.x * inv_f, e.y * inv_f, e.z * inv_f, e.w * inv_f);
    *reinterpret_cast<float4*>(ep) = f4;
    ushort4 u;
    u.x = f2bf(e.x); u.y = f2bf(e.y); u.z = f2bf(e.z); u.w = f2bf(e.w);
    {
      int slot = ec >> 3, off = ec & 7;
      *reinterpret_cast<ushort4*>(
          &As2[erow * 32 + ((slot ^ ((erow >> 1) & 3)) * 8) + off]) = u;
    }
    const unsigned short* vs_src = vt_base + (size_t)si * 24576;
#pragma unroll
    for (int j = 0; j < 6; ++j)
      gl_lds16(vs_src + j * 4096, (char*)Vs + (size_t)(j * 512 + wave * 64) * 16);
    __syncthreads();
    if (si + 1 < NSTEP) e = *reinterpret_cast<const float4*>(ep + 32);
    ep += 32;
    bf16x8 a[2];
#pragma unroll
    for (int m = 0; m < 2; ++m) {
      int R = wr * 32 + m * 16 + (lane & 15);
      a[m] = *reinterpret_cast<const bf16x8*>(&As2[R * 32 + ((q ^ ((R >> 1) & 3)) * 8)]);
    }
#pragma unroll
    for (int n = 0; n < 12; ++n) {
      int C = wc * 192 + n * 16 + (lane & 15);
      bf16x8 b = *reinterpret_cast<const bf16x8*>(&Vs[C * 32 + ((q ^ ((C >> 1) & 3)) * 8)]);
      acc[0][n] = __builtin_amdgcn_mfma_f32_16x16x32_bf16(a[0], b, acc[0][n], 0, 0, 0);
      acc[1][n] = __builtin_amdgcn_mfma_f32_16x16x32_bf16(a[1], b, acc[1][n], 0, 0, 0);
    }
    __syncthreads();
  }

  unsigned short* P = partial + (size_t)ks * B_ * D_;
#pragma unroll
  for (int m = 0; m < 2; ++m) {
    int rowb = r0 + wr * 32 + m * 16 + q * 4;
#pragma unroll
    for (int r = 0; r < 4; ++r) {
      float inv = 1.0f / rowsum[rowb + r];
      size_t row_off = (size_t)(rowb + r) * D_;
#pragma unroll
      for (int n = 0; n < 12; ++n) {
        int col = wc * 192 + n * 16 + (lane & 15);
        P[row_off + col] = f2bf(acc[m][n][r] * inv);
      }
    }
  }
}

// ---------------- sum nks bf16 partials -> f32 x_hat -------------------------------
__global__ void reduce_kernel(const unsigned short* __restrict__ partial,
                              float* __restrict__ out, int n8, int nks) {
  int i = blockIdx.x * blockDim.x + threadIdx.x;
  if (i >= n8) return;
  size_t base = (size_t)i * 8;
  float s[8] = {0.f, 0.f, 0.f, 0.f, 0.f, 0.f, 0.f, 0.f};
  for (int ks = 0; ks < nks; ++ks) {
    ushort8 v = *reinterpret_cast<const ushort8*>(&partial[(size_t)ks * B_ * D_ + base]);
#pragma unroll
    for (int j = 0; j < 8; ++j) s[j] += bf2f(v[j]);
  }
  float4 o0 = make_float4(s[0], s[1], s[2], s[3]);
  float4 o1 = make_float4(s[4], s[5], s[6], s[7]);
  *reinterpret_cast<float4*>(&out[base]) = o0;
  *reinterpret_cast<float4*>(&out[base + 4]) = o1;
}

extern "C" void kernel_launch(void* const* d_in, const int* in_sizes, int n_in,
                              void* d_out, int out_size, void* d_ws, size_t ws_size,
                              hipStream_t stream) {
  const float* x = (const float*)d_in[0];
  const float* mb = (const float*)d_in[1];
  const float* Wq = (const float*)d_in[2];
  const float* bq = (const float*)d_in[3];
  const float* Wk = (const float*)d_in[4];
  const float* bk = (const float*)d_in[5];
  const float* Wv = (const float*)d_in[6];
  const float* bv = (const float*)d_in[7];
  const float* temp = (const float*)d_in[8];

  float* out_x = (float*)d_out;
  float* out_xhat = out_x + (size_t)B_ * D_;
  float* out_f = out_xhat + (size_t)B_ * D_;
  float* out_V = out_f + (size_t)B_ * F_;

  char* ws = (char*)d_ws;
  const size_t WS_NEED_NEW = 220217344;  // new-path peak usage (partial KS=8)

  if (ws_size >= WS_NEED_NEW) {
    // ---------- r12 path + KS=8 xhat grid (4 blocks/CU) ----------
    unsigned short* Qb  = (unsigned short*)(ws + 0);          // 2097152
    unsigned short* Kb  = (unsigned short*)(ws + 2097152);    // 8388608
    unsigned short* Vtt = (unsigned short*)(ws + 10485760);   // 25165824
    float* rowsum       = (float*)(ws + 35651584);            // 16384
    char* A0 = ws + 35667968;                                 // cast area / E_tiled
    unsigned short* xb  = (unsigned short*)(A0 + 0);          // 6291456
    unsigned short* mbb = (unsigned short*)(A0 + 6291456);    // 25165824
    unsigned short* Wqb = (unsigned short*)(A0 + 31457280);   // 393216
    unsigned short* Wkb = (unsigned short*)(A0 + 31850496);   // 393216
    unsigned short* Wvb = (unsigned short*)(A0 + 32243712);   // 1179648
    unsigned short* Et  = (unsigned short*)A0;                // 134217728 (overlays casts)
    unsigned short* partial = (unsigned short*)(ws + 169885696); // 8*6291456 = 50331648

    hipMemsetAsync(rowsum, 0, B_ * sizeof(float), stream);

    cast_all<<<(CAST_UNITS + 255) / 256, 256, 0, stream>>>(x, mb, Wq, Wk, Wv, xb, mbb,
                                                           Wqb, Wkb, Wvb, out_x);

    dim3 blk(256);
    gemm_bt<0><<<dim3(M_ / 128, B_ / 128), blk, 0, stream>>>(xb, Wqb, bq, nullptr, Qb,
                                                             B_, M_, D_, nullptr, nullptr);
    gemm_bt<0><<<dim3(M_ / 128, F_ / 128), blk, 0, stream>>>(mbb, Wkb, bk, nullptr, Kb,
                                                             F_, M_, D_, nullptr, nullptr);
    gemm_bt<1><<<dim3(D_ / 128, F_ / 128), blk, 0, stream>>>(mbb, Wvb, bv, out_V, nullptr,
                                                             F_, D_, D_, nullptr, nullptr);
    vt_tiler<<<dim3(F_ / 32), 256, 0, stream>>>(out_V, Vtt);
    // E (bf16 tiled, overlays dead cast buffers) + rowsum
    gemm_bt<3><<<dim3(F_ / 128, B_ / 128), blk, 0, stream>>>(Qb, Kb, nullptr, nullptr, Et,
                                                             B_, F_, M_, rowsum, temp);
    normalize_f<<<dim3(B_ * F_ / 8 / 256), 256, 0, stream>>>(Et, rowsum, out_f);
    xhat_clean<<<dim3(1024), dim3(512), 0, stream>>>(Et, Vtt, rowsum, partial);
    reduce_kernel<<<(B_ * D_ / 8 + 255) / 256, 256, 0, stream>>>(partial, out_xhat,
                                                                 B_ * D_ / 8, 8);
  } else {
    // ---------- fallback: round-4 proven pipeline ----------
    unsigned short* xb  = (unsigned short*)(ws + 0);
    unsigned short* mbb = (unsigned short*)(ws + 6291456);
    unsigned short* Wqb = (unsigned short*)(ws + 31457280);
    unsigned short* Wkb = (unsigned short*)(ws + 31850496);
    unsigned short* Wvb = (unsigned short*)(ws + 32243712);
    unsigned short* Qb  = (unsigned short*)(ws + 33423360);
    unsigned short* Kb  = (unsigned short*)(ws + 35520512);
    unsigned short* Vtt = (unsigned short*)(ws + 43909120);
    float* rowsum       = (float*)(ws + 69074944);
    unsigned short* partial = (unsigned short*)(ws + 69091328);

    hipMemsetAsync(rowsum, 0, B_ * sizeof(float), stream);

    cast_all<<<(CAST_UNITS + 255) / 256, 256, 0, stream>>>(x, mb, Wq, Wk, Wv, xb, mbb,
                                                           Wqb, Wkb, Wvb, out_x);

    dim3 blk(256);
    gemm_bt<0><<<dim3(M_ / 128, B_ / 128), blk, 0, stream>>>(xb, Wqb, bq, nullptr, Qb,
                                                             B_, M_, D_, nullptr, nullptr);
    gemm_bt<0><<<dim3(M_ / 128, F_ / 128), blk, 0, stream>>>(mbb, Wkb, bk, nullptr, Kb,
                                                             F_, M_, D_, nullptr, nullptr);
    gemm_bt<1><<<dim3(D_ / 128, F_ / 128), blk, 0, stream>>>(mbb, Wvb, bv, out_V, nullptr,
                                                             F_, D_, D_, nullptr, nullptr);
    vt_tiler<<<dim3(F_ / 32), 256, 0, stream>>>(out_V, Vtt);
    gemm_bt<2><<<dim3(F_ / 128, B_ / 128), blk, 0, stream>>>(Qb, Kb, nullptr, out_f, nullptr,
                                                             B_, F_, M_, rowsum, temp);
    xhat_v4<<<dim3(512), dim3(512), 0, stream>>>(out_f, Vtt, rowsum, partial);
    reduce_kernel<<<(B_ * D_ / 8 + 255) / 256, 256, 0, stream>>>(partial, out_xhat,
                                                                 B_ * D_ / 8, 8);
  }
}

// Round 15
// 428.152 us; speedup vs baseline: 1.0462x; 1.0462x over previous
//
#include <hip/hip_runtime.h>
#include <stdint.h>

#define B_ 4096
#define D_ 768
#define F_ 16384
#define M_ 256

typedef short bf16x8 __attribute__((ext_vector_type(8)));
typedef float f32x4 __attribute__((ext_vector_type(4)));
typedef unsigned short ushort8 __attribute__((ext_vector_type(8)));

__device__ __forceinline__ unsigned short f2bf(float f) {
  union { float f; uint32_t u; } c; c.f = f;
  uint32_t u = c.u;
  uint32_t r = (u + 0x7FFFu + ((u >> 16) & 1u)) >> 16;
  return (unsigned short)r;
}

__device__ __forceinline__ float bf2f(unsigned short s) {
  union { uint32_t u; float f; } c; c.u = ((uint32_t)s) << 16;
  return c.f;
}

__device__ __forceinline__ void gl_lds16(const void* g, void* l) {
  __builtin_amdgcn_global_load_lds(
      (const __attribute__((address_space(1))) unsigned int*)g,
      (__attribute__((address_space(3))) unsigned int*)l, 16, 0, 0);
}

// ---------------- fused f32 -> bf16 casts for all 5 inputs (one launch) ------------
__global__ void cast_all(const float* __restrict__ x, const float* __restrict__ mb,
                         const float* __restrict__ Wq, const float* __restrict__ Wk,
                         const float* __restrict__ Wv,
                         unsigned short* __restrict__ xb, unsigned short* __restrict__ mbb,
                         unsigned short* __restrict__ Wqb, unsigned short* __restrict__ Wkb,
                         unsigned short* __restrict__ Wvb, float* __restrict__ out_x) {
  int i = blockIdx.x * blockDim.x + threadIdx.x;  // float4 units
  const int NX = B_ * D_ / 4;    // 786432
  const int NMB = F_ * D_ / 4;   // 3145728
  const int NW = M_ * D_ / 4;    // 49152
  const int NWV = D_ * D_ / 4;   // 147456
  const float* src;
  unsigned short* dst;
  float* cpy = nullptr;
  int off;
  if (i < NX) { src = x; dst = xb; off = i; cpy = out_x; }
  else if ((i -= NX) < NMB) { src = mb; dst = mbb; off = i; }
  else if ((i -= NMB) < NW) { src = Wq; dst = Wqb; off = i; }
  else if ((i -= NW) < NW) { src = Wk; dst = Wkb; off = i; }
  else if ((i -= NW) < NWV) { src = Wv; dst = Wvb; off = i; }
  else return;
  float4 v = reinterpret_cast<const float4*>(src)[off];
  ushort4 u;
  u.x = f2bf(v.x); u.y = f2bf(v.y); u.z = f2bf(v.z); u.w = f2bf(v.w);
  reinterpret_cast<ushort4*>(dst)[off] = u;
  if (cpy) reinterpret_cast<float4*>(cpy)[off] = v;
}
#define CAST_UNITS (B_ * D_ / 4 + F_ * D_ / 4 + 2 * (M_ * D_ / 4) + D_ * D_ / 4)

// ---------------- gemm_bt: C[M,N] = A[M,K] * B[N,K]^T  (both bf16 K-contiguous) ----
// EPI 0: store bf16 (+bias)   EPI 1: store f32 (+bias)
// EPI 2: exp(c/temp) -> f32 E + rowsum      (fallback path)
// EPI 3: exp(c/temp) -> bf16 TILED E via LDS restage (coalesced ushort8) + rowsum
template <int EPI>
__global__ __launch_bounds__(256, 2) void gemm_bt(
    const unsigned short* __restrict__ A, const unsigned short* __restrict__ Bm,
    const float* __restrict__ bias, float* __restrict__ Cf,
    unsigned short* __restrict__ Cb, int M, int N, int K,
    float* __restrict__ rowsum, const float* __restrict__ tptr) {
  __shared__ unsigned short As[128 * 32];
  __shared__ unsigned short Bs[128 * 32];
  const int tid = threadIdx.x, lane = tid & 63, wave = tid >> 6;
  const int m0 = blockIdx.y * 128, n0 = blockIdx.x * 128;
  const int wr = wave >> 1, wc = wave & 1;
  const int q = lane >> 4;
  f32x4 acc[4][4] = {};

  for (int k0 = 0; k0 < K; k0 += 32) {
#pragma unroll
    for (int i = 0; i < 2; ++i) {
      int cb = (i * 4 + wave) * 64;
      int ch = cb + lane;
      int row = ch >> 2, ko = (ch & 3) * 8;
      gl_lds16(A + (size_t)(m0 + row) * K + k0 + ko, (char*)As + (size_t)cb * 16);
      gl_lds16(Bm + (size_t)(n0 + row) * K + k0 + ko, (char*)Bs + (size_t)cb * 16);
    }
    __syncthreads();
    bf16x8 a[4];
#pragma unroll
    for (int m = 0; m < 4; ++m)
      a[m] = *reinterpret_cast<const bf16x8*>(
          &As[(wr * 64 + m * 16 + (lane & 15)) * 32 + q * 8]);
#pragma unroll
    for (int n = 0; n < 4; ++n) {
      bf16x8 b = *reinterpret_cast<const bf16x8*>(
          &Bs[(wc * 64 + n * 16 + (lane & 15)) * 32 + q * 8]);
#pragma unroll
      for (int m = 0; m < 4; ++m)
        acc[m][n] = __builtin_amdgcn_mfma_f32_16x16x32_bf16(a[m], b, acc[m][n], 0, 0, 0);
    }
    __syncthreads();
  }

  const int rbase = m0 + wr * 64 + q * 4;
  const int cbase = n0 + wc * 64 + (lane & 15);
  if constexpr (EPI == 3) {
    __shared__ unsigned short Cs[128 * 128];   // 32 KB restage tile
    const float invt = 1.0f / tptr[0];
    const int rl0 = wr * 64 + q * 4, cl0 = wc * 64 + (lane & 15);
#pragma unroll
    for (int m = 0; m < 4; ++m) {
      float rs[4] = {0.f, 0.f, 0.f, 0.f};
#pragma unroll
      for (int n = 0; n < 4; ++n) {
#pragma unroll
        for (int r = 0; r < 4; ++r) {
          float e = __expf(acc[m][n][r] * invt);
          rs[r] += e;
          Cs[(rl0 + m * 16 + r) * 128 + cl0 + n * 16] = f2bf(e);
        }
      }
#pragma unroll
      for (int r = 0; r < 4; ++r) {
        float s = rs[r];
        s += __shfl_xor(s, 1);
        s += __shfl_xor(s, 2);
        s += __shfl_xor(s, 4);
        s += __shfl_xor(s, 8);
        if ((lane & 15) == 0) atomicAdd(&rowsum[rbase + m * 16 + r], s);
      }
    }
    __syncthreads();
    // coalesced tiled-E writeout: 2048 ushort8 units, 8 per thread
    const size_t ebase = ((size_t)(m0 >> 7) * 512 + (n0 >> 5)) * 4096;
#pragma unroll
    for (int j = 0; j < 8; ++j) {
      int u = j * 256 + tid;
      int tl = u >> 9, r = (u >> 2) & 127, p = u & 3;
      ushort8 v = *reinterpret_cast<const ushort8*>(
          &Cs[r * 128 + tl * 32 + ((p ^ ((r >> 1) & 3)) * 8)]);
      *reinterpret_cast<ushort8*>(&Cb[ebase + (size_t)tl * 4096 + r * 32 + p * 8]) = v;
    }
  } else if constexpr (EPI == 2) {
    const float invt = 1.0f / tptr[0];
#pragma unroll
    for (int m = 0; m < 4; ++m) {
      float rs[4] = {0.f, 0.f, 0.f, 0.f};
#pragma unroll
      for (int n = 0; n < 4; ++n) {
        int col = cbase + n * 16;
#pragma unroll
        for (int r = 0; r < 4; ++r) {
          float e = __expf(acc[m][n][r] * invt);
          Cf[(size_t)(rbase + m * 16 + r) * N + col] = e;
          rs[r] += e;
        }
      }
#pragma unroll
      for (int r = 0; r < 4; ++r) {
        float s = rs[r];
        s += __shfl_xor(s, 1);
        s += __shfl_xor(s, 2);
        s += __shfl_xor(s, 4);
        s += __shfl_xor(s, 8);
        if ((lane & 15) == 0) atomicAdd(&rowsum[rbase + m * 16 + r], s);
      }
    }
  } else {
#pragma unroll
    for (int m = 0; m < 4; ++m) {
#pragma unroll
      for (int n = 0; n < 4; ++n) {
        int col = cbase + n * 16;
        float bv = bias[col];
#pragma unroll
        for (int r = 0; r < 4; ++r) {
          float v = acc[m][n][r] + bv;
          size_t idx = (size_t)(rbase + m * 16 + r) * N + col;
          if (EPI == 0) Cb[idx] = f2bf(v);
          else Cf[idx] = v;
        }
      }
    }
  }
}

// ---------------- V[16384,768] f32 -> Vt_tiled bf16 --------------------------------
// Tile t: 48KB contiguous; xhat LDS image with XOR slot-swizzle pre-applied:
//   Vt_tiled[t*24576 + d*32 + s*8 + o] = bf16( V[t*32 + (s^((d>>1)&3))*8 + o][d] )
__global__ __launch_bounds__(256) void vt_tiler(const float* __restrict__ V,
                                                unsigned short* __restrict__ Vt_tiled) {
  __shared__ unsigned short T[768][36];
  const int t = blockIdx.x, k0 = t * 32, tid = threadIdx.x;
  const int kl = tid >> 3, c0 = (tid & 7) * 4;
  for (int cb = 0; cb < 768; cb += 32) {
    float4 v = *reinterpret_cast<const float4*>(&V[(size_t)(k0 + kl) * D_ + cb + c0]);
    T[cb + c0 + 0][kl] = f2bf(v.x);
    T[cb + c0 + 1][kl] = f2bf(v.y);
    T[cb + c0 + 2][kl] = f2bf(v.z);
    T[cb + c0 + 3][kl] = f2bf(v.w);
  }
  __syncthreads();
  for (int d = tid; d < 768; d += 256) {
    const int x = (d >> 1) & 3;
    unsigned short* o = Vt_tiled + (size_t)t * 24576 + d * 32;
#pragma unroll
    for (int s = 0; s < 4; ++s) {
      ushort4 lo = *reinterpret_cast<const ushort4*>(&T[d][(s ^ x) * 8]);
      ushort4 hi = *reinterpret_cast<const ushort4*>(&T[d][(s ^ x) * 8 + 4]);
      *reinterpret_cast<ushort4*>(o + s * 8) = lo;
      *reinterpret_cast<ushort4*>(o + s * 8 + 4) = hi;
    }
  }
}

// ---------------- xhat (round-8/12 proven): 512-thr 8-wave, BK=64, KS=4 ------------
// partial[ks][128x192 tile] = (E_chunk @ V_chunk) * diag(1/rowsum), bf16.
// Wave grid 2x4, wave tile 64x48, acc[4][3]. Waves 0-3 stage A (4 chunks each = 16),
// waves 4-7 stage B (6 chunks each = 24 = 192rows x 64k). 64 steps, 48 MFMA/wave.
// combo = bid&15 (ks=combo>>2, nb=combo&3), mb = bid>>4 -> same-combo blocks share
// an XCD (%8 round-robin): 2 V-panels x 1.5MB = 3MB < 4MB L2.
__global__ __launch_bounds__(512, 4) void xhat_clean(
    const unsigned short* __restrict__ Et, const unsigned short* __restrict__ Vtt,
    const float* __restrict__ rowsum, unsigned short* __restrict__ partial) {
  __shared__ unsigned short As[2][128 * 32];   // 16 KB
  __shared__ unsigned short Bs[2][192 * 32];   // 24 KB
  const int tid = threadIdx.x, lane = tid & 63, wave = tid >> 6;
  const int combo = blockIdx.x & 15, mb = blockIdx.x >> 4;
  const int ks = combo >> 2, nb = combo & 3;
  const int q = lane >> 4;
  const int wr = wave >> 2, wc = wave & 3;  // wave tile 64r x 48c
  const int t0 = ks * 128;
  f32x4 acc[4][3] = {};

  const unsigned short* abase =
      Et + ((size_t)mb * 512 + t0) * 4096 + lane * 8;
  const unsigned short* bbase =
      Vtt + (size_t)t0 * 24576 + nb * 6144 + lane * 8;

  for (int si = 0; si < 64; ++si) {
    const size_t tA = (size_t)(2 * si) * 4096;
    const size_t tB = (size_t)(2 * si) * 24576;
    if (wave < 4) {
      // A: 128r x 64k = 16 chunks of 512 shorts; 4 per wave
#pragma unroll
      for (int j = 0; j < 4; ++j) {
        int c = wave * 4 + j;         // 0..15
        int h = c >> 3, cw = c & 7;
        gl_lds16(abase + tA + (size_t)h * 4096 + cw * 512,
                 (char*)As + h * 8192 + cw * 1024);
      }
    } else {
      // B: 192r x 64k = 24 chunks of 512 shorts; 6 per wave
#pragma unroll
      for (int j = 0; j < 6; ++j) {
        int c = (wave - 4) * 6 + j;   // 0..23
        int h = c / 12, cc = c % 12;
        gl_lds16(bbase + tB + (size_t)h * 24576 + cc * 512,
                 (char*)Bs + h * 12288 + cc * 1024);
      }
    }
    __syncthreads();
#pragma unroll
    for (int h = 0; h < 2; ++h) {
      bf16x8 a[4], b[3];
#pragma unroll
      for (int m = 0; m < 4; ++m) {
        int R = wr * 64 + m * 16 + (lane & 15);
        a[m] = *reinterpret_cast<const bf16x8*>(
            &As[h][R * 32 + ((q ^ ((R >> 1) & 3)) * 8)]);
      }
#pragma unroll
      for (int n = 0; n < 3; ++n) {
        int C = wc * 48 + n * 16 + (lane & 15);
        b[n] = *reinterpret_cast<const bf16x8*>(
            &Bs[h][C * 32 + ((q ^ ((C >> 1) & 3)) * 8)]);
      }
#pragma unroll
      for (int n = 0; n < 3; ++n)
#pragma unroll
        for (int m = 0; m < 4; ++m)
          acc[m][n] = __builtin_amdgcn_mfma_f32_16x16x32_bf16(a[m], b[n], acc[m][n], 0, 0, 0);
    }
    __syncthreads();
  }

  unsigned short* P = partial + (size_t)ks * B_ * D_;
#pragma unroll
  for (int m = 0; m < 4; ++m) {
    int rowb = mb * 128 + wr * 64 + m * 16 + q * 4;
#pragma unroll
    for (int r = 0; r < 4; ++r) {
      float inv = 1.0f / rowsum[rowb + r];
      size_t ro = (size_t)(rowb + r) * D_;
#pragma unroll
      for (int n = 0; n < 3; ++n) {
        int col = nb * 192 + wc * 48 + n * 16 + (lane & 15);
        P[ro + col] = f2bf(acc[m][n][r] * inv);
      }
    }
  }
}

// ---------------- fused tail: x_hat reduce (nks=4) + f normalize in one launch -----
// Unit ranges: [0, NRED) -> reduce (8 floats of x_hat each);
//              [NRED, NRED + B_*F_/8) -> normalize (8 f elems each).
// Bodies verbatim from the proven reduce_kernel / normalize_f.
__global__ __launch_bounds__(256) void norm_reduce(
    const unsigned short* __restrict__ partial, float* __restrict__ out_xhat,
    const unsigned short* __restrict__ Et, const float* __restrict__ rowsum,
    float* __restrict__ f) {
  const int NRED = B_ * D_ / 8;  // 393216
  int i = blockIdx.x * blockDim.x + threadIdx.x;
  if (i < NRED) {
    size_t base = (size_t)i * 8;
    float s[8] = {0.f, 0.f, 0.f, 0.f, 0.f, 0.f, 0.f, 0.f};
#pragma unroll
    for (int ks = 0; ks < 4; ++ks) {
      ushort8 v = *reinterpret_cast<const ushort8*>(&partial[(size_t)ks * B_ * D_ + base]);
#pragma unroll
      for (int j = 0; j < 8; ++j) s[j] += bf2f(v[j]);
    }
    float4 o0 = make_float4(s[0], s[1], s[2], s[3]);
    float4 o1 = make_float4(s[4], s[5], s[6], s[7]);
    *reinterpret_cast<float4*>(&out_xhat[base]) = o0;
    *reinterpret_cast<float4*>(&out_xhat[base + 4]) = o1;
    return;
  }
  int u = i - NRED;
  if (u >= B_ * F_ / 8) return;
  int g = u >> 9, w = u & 511;                    // 512 units per 128x32 tile
  int r = w >> 2, p = w & 3;
  int rb = g >> 9, t = g & 511;
  int row = rb * 128 + r;
  int col = t * 32 + (p ^ ((r >> 1) & 3)) * 8;
  float inv = 1.0f / rowsum[row];
  ushort8 e = *reinterpret_cast<const ushort8*>(&Et[(size_t)g * 4096 + w * 8]);
  float4 o0, o1;
  o0.x = bf2f(e[0]) * inv; o0.y = bf2f(e[1]) * inv;
  o0.z = bf2f(e[2]) * inv; o0.w = bf2f(e[3]) * inv;
  o1.x = bf2f(e[4]) * inv; o1.y = bf2f(e[5]) * inv;
  o1.z = bf2f(e[6]) * inv; o1.w = bf2f(e[7]) * inv;
  float* fp = &f[(size_t)row * F_ + col];
  *reinterpret_cast<float4*>(fp) = o0;
  *reinterpret_cast<float4*>(fp + 4) = o1;
}

// ---------------- xhat v4 (fallback, round-4 proven) -------------------------------
__global__ __launch_bounds__(512, 4) void xhat_v4(
    float* __restrict__ Ef, const unsigned short* __restrict__ Vt_tiled,
    const float* __restrict__ rowsum, unsigned short* __restrict__ partial) {
  __shared__ unsigned short As2[64 * 32];
  __shared__ unsigned short Vs[768 * 32];
  const int tid = threadIdx.x, lane = tid & 63, wave = tid >> 6;
  const int ks = blockIdx.x & 7, rb = blockIdx.x >> 3;
  const int r0 = rb * 64;
  const int kbeg = ks * (F_ / 8);
  const int wr = wave >> 2, wc = wave & 3;
  const int erow = tid >> 3, ec = (tid & 7) * 4;
  const float inv_f = 1.0f / rowsum[r0 + erow];
  const int q = lane >> 4;
  f32x4 acc[2][12] = {};

  float* ep = Ef + (size_t)(r0 + erow) * F_ + kbeg + ec;
  float4 e = *reinterpret_cast<const float4*>(ep);
  const int NSTEP = (F_ / 8) / 32;
  const unsigned short* vt_base =
      Vt_tiled + (size_t)(kbeg >> 5) * 24576 + wave * 512 + lane * 8;

  for (int si = 0; si < NSTEP; ++si) {
    float4 f4 = make_float4(e.x * inv_f, e.y * inv_f, e.z * inv_f, e.w * inv_f);
    *reinterpret_cast<float4*>(ep) = f4;
    ushort4 u;
    u.x = f2bf(e.x); u.y = f2bf(e.y); u.z = f2bf(e.z); u.w = f2bf(e.w);
    {
      int slot = ec >> 3, off = ec & 7;
      *reinterpret_cast<ushort4*>(
          &As2[erow * 32 + ((slot ^ ((erow >> 1) & 3)) * 8) + off]) = u;
    }
    const unsigned short* vs_src = vt_base + (size_t)si * 24576;
#pragma unroll
    for (int j = 0; j < 6; ++j)
      gl_lds16(vs_src + j * 4096, (char*)Vs + (size_t)(j * 512 + wave * 64) * 16);
    __syncthreads();
    if (si + 1 < NSTEP) e = *reinterpret_cast<const float4*>(ep + 32);
    ep += 32;
    bf16x8 a[2];
#pragma unroll
    for (int m = 0; m < 2; ++m) {
      int R = wr * 32 + m * 16 + (lane & 15);
      a[m] = *reinterpret_cast<const bf16x8*>(&As2[R * 32 + ((q ^ ((R >> 1) & 3)) * 8)]);
    }
#pragma unroll
    for (int n = 0; n < 12; ++n) {
      int C = wc * 192 + n * 16 + (lane & 15);
      bf16x8 b = *reinterpret_cast<const bf16x8*>(&Vs[C * 32 + ((q ^ ((C >> 1) & 3)) * 8)]);
      acc[0][n] = __builtin_amdgcn_mfma_f32_16x16x32_bf16(a[0], b, acc[0][n], 0, 0, 0);
      acc[1][n] = __builtin_amdgcn_mfma_f32_16x16x32_bf16(a[1], b, acc[1][n], 0, 0, 0);
    }
    __syncthreads();
  }

  unsigned short* P = partial + (size_t)ks * B_ * D_;
#pragma unroll
  for (int m = 0; m < 2; ++m) {
    int rowb = r0 + wr * 32 + m * 16 + q * 4;
#pragma unroll
    for (int r = 0; r < 4; ++r) {
      float inv = 1.0f / rowsum[rowb + r];
      size_t row_off = (size_t)(rowb + r) * D_;
#pragma unroll
      for (int n = 0; n < 12; ++n) {
        int col = wc * 192 + n * 16 + (lane & 15);
        P[row_off + col] = f2bf(acc[m][n][r] * inv);
      }
    }
  }
}

// ---------------- sum nks bf16 partials -> f32 x_hat (fallback path) ---------------
__global__ void reduce_kernel(const unsigned short* __restrict__ partial,
                              float* __restrict__ out, int n8, int nks) {
  int i = blockIdx.x * blockDim.x + threadIdx.x;
  if (i >= n8) return;
  size_t base = (size_t)i * 8;
  float s[8] = {0.f, 0.f, 0.f, 0.f, 0.f, 0.f, 0.f, 0.f};
  for (int ks = 0; ks < nks; ++ks) {
    ushort8 v = *reinterpret_cast<const ushort8*>(&partial[(size_t)ks * B_ * D_ + base]);
#pragma unroll
    for (int j = 0; j < 8; ++j) s[j] += bf2f(v[j]);
  }
  float4 o0 = make_float4(s[0], s[1], s[2], s[3]);
  float4 o1 = make_float4(s[4], s[5], s[6], s[7]);
  *reinterpret_cast<float4*>(&out[base]) = o0;
  *reinterpret_cast<float4*>(&out[base + 4]) = o1;
}

extern "C" void kernel_launch(void* const* d_in, const int* in_sizes, int n_in,
                              void* d_out, int out_size, void* d_ws, size_t ws_size,
                              hipStream_t stream) {
  const float* x = (const float*)d_in[0];
  const float* mb = (const float*)d_in[1];
  const float* Wq = (const float*)d_in[2];
  const float* bq = (const float*)d_in[3];
  const float* Wk = (const float*)d_in[4];
  const float* bk = (const float*)d_in[5];
  const float* Wv = (const float*)d_in[6];
  const float* bv = (const float*)d_in[7];
  const float* temp = (const float*)d_in[8];

  float* out_x = (float*)d_out;
  float* out_xhat = out_x + (size_t)B_ * D_;
  float* out_f = out_xhat + (size_t)B_ * D_;
  float* out_V = out_f + (size_t)B_ * F_;

  char* ws = (char*)d_ws;
  const size_t WS_NEED_NEW = 195051520;  // new-path peak usage

  if (ws_size >= WS_NEED_NEW) {
    // ---------- r12 proven path, normalize+reduce fused into one tail launch -------
    unsigned short* Qb  = (unsigned short*)(ws + 0);          // 2097152
    unsigned short* Kb  = (unsigned short*)(ws + 2097152);    // 8388608
    unsigned short* Vtt = (unsigned short*)(ws + 10485760);   // 25165824
    float* rowsum       = (float*)(ws + 35651584);            // 16384
    char* A0 = ws + 35667968;                                 // cast area / E_tiled
    unsigned short* xb  = (unsigned short*)(A0 + 0);          // 6291456
    unsigned short* mbb = (unsigned short*)(A0 + 6291456);    // 25165824
    unsigned short* Wqb = (unsigned short*)(A0 + 31457280);   // 393216
    unsigned short* Wkb = (unsigned short*)(A0 + 31850496);   // 393216
    unsigned short* Wvb = (unsigned short*)(A0 + 32243712);   // 1179648
    unsigned short* Et  = (unsigned short*)A0;                // 134217728 (overlays casts)
    unsigned short* partial = (unsigned short*)(ws + 169885696); // 4*6291456 = 25165824

    hipMemsetAsync(rowsum, 0, B_ * sizeof(float), stream);

    cast_all<<<(CAST_UNITS + 255) / 256, 256, 0, stream>>>(x, mb, Wq, Wk, Wv, xb, mbb,
                                                           Wqb, Wkb, Wvb, out_x);

    dim3 blk(256);
    gemm_bt<0><<<dim3(M_ / 128, B_ / 128), blk, 0, stream>>>(xb, Wqb, bq, nullptr, Qb,
                                                             B_, M_, D_, nullptr, nullptr);
    gemm_bt<0><<<dim3(M_ / 128, F_ / 128), blk, 0, stream>>>(mbb, Wkb, bk, nullptr, Kb,
                                                             F_, M_, D_, nullptr, nullptr);
    gemm_bt<1><<<dim3(D_ / 128, F_ / 128), blk, 0, stream>>>(mbb, Wvb, bv, out_V, nullptr,
                                                             F_, D_, D_, nullptr, nullptr);
    vt_tiler<<<dim3(F_ / 32), 256, 0, stream>>>(out_V, Vtt);
    // E (bf16 tiled, overlays dead cast buffers) + rowsum
    gemm_bt<3><<<dim3(F_ / 128, B_ / 128), blk, 0, stream>>>(Qb, Kb, nullptr, nullptr, Et,
                                                             B_, F_, M_, rowsum, temp);
    // xhat immediately after scores (Et hottest in L2/L3)
    xhat_clean<<<dim3(512), dim3(512), 0, stream>>>(Et, Vtt, rowsum, partial);
    // fused tail: x_hat reduce + f normalize
    const int NTAIL = B_ * D_ / 8 + B_ * F_ / 8;
    norm_reduce<<<(NTAIL + 255) / 256, 256, 0, stream>>>(partial, out_xhat, Et, rowsum,
                                                         out_f);
  } else {
    // ---------- fallback: round-4 proven pipeline ----------
    unsigned short* xb  = (unsigned short*)(ws + 0);
    unsigned short* mbb = (unsigned short*)(ws + 6291456);
    unsigned short* Wqb = (unsigned short*)(ws + 31457280);
    unsigned short* Wkb = (unsigned short*)(ws + 31850496);
    unsigned short* Wvb = (unsigned short*)(ws + 32243712);
    unsigned short* Qb  = (unsigned short*)(ws + 33423360);
    unsigned short* Kb  = (unsigned short*)(ws + 35520512);
    unsigned short* Vtt = (unsigned short*)(ws + 43909120);
    float* rowsum       = (float*)(ws + 69074944);
    unsigned short* partial = (unsigned short*)(ws + 69091328);

    hipMemsetAsync(rowsum, 0, B_ * sizeof(float), stream);

    cast_all<<<(CAST_UNITS + 255) / 256, 256, 0, stream>>>(x, mb, Wq, Wk, Wv, xb, mbb,
                                                           Wqb, Wkb, Wvb, out_x);

    dim3 blk(256);
    gemm_bt<0><<<dim3(M_ / 128, B_ / 128), blk, 0, stream>>>(xb, Wqb, bq, nullptr, Qb,
                                                             B_, M_, D_, nullptr, nullptr);
    gemm_bt<0><<<dim3(M_ / 128, F_ / 128), blk, 0, stream>>>(mbb, Wkb, bk, nullptr, Kb,
                                                             F_, M_, D_, nullptr, nullptr);
    gemm_bt<1><<<dim3(D_ / 128, F_ / 128), blk, 0, stream>>>(mbb, Wvb, bv, out_V, nullptr,
                                                             F_, D_, D_, nullptr, nullptr);
    vt_tiler<<<dim3(F_ / 32), 256, 0, stream>>>(out_V, Vtt);
    gemm_bt<2><<<dim3(F_ / 128, B_ / 128), blk, 0, stream>>>(Qb, Kb, nullptr, out_f, nullptr,
                                                             B_, F_, M_, rowsum, temp);
    xhat_v4<<<dim3(512), dim3(512), 0, stream>>>(out_f, Vtt, rowsum, partial);
    reduce_kernel<<<(B_ * D_ / 8 + 255) / 256, 256, 0, stream>>>(partial, out_xhat,
                                                                 B_ * D_ / 8, 8);
  }
}

// Round 16
// 408.603 us; speedup vs baseline: 1.0962x; 1.0478x over previous
//
#include <hip/hip_runtime.h>
#include <stdint.h>

#define B_ 4096
#define D_ 768
#define F_ 16384
#define M_ 256

typedef short bf16x8 __attribute__((ext_vector_type(8)));
typedef float f32x4 __attribute__((ext_vector_type(4)));
typedef unsigned short ushort8 __attribute__((ext_vector_type(8)));

__device__ __forceinline__ unsigned short f2bf(float f) {
  union { float f; uint32_t u; } c; c.f = f;
  uint32_t u = c.u;
  uint32_t r = (u + 0x7FFFu + ((u >> 16) & 1u)) >> 16;
  return (unsigned short)r;
}

__device__ __forceinline__ float bf2f(unsigned short s) {
  union { uint32_t u; float f; } c; c.u = ((uint32_t)s) << 16;
  return c.f;
}

__device__ __forceinline__ void gl_lds16(const void* g, void* l) {
  __builtin_amdgcn_global_load_lds(
      (const __attribute__((address_space(1))) unsigned int*)g,
      (__attribute__((address_space(3))) unsigned int*)l, 16, 0, 0);
}

// ---------------- fused f32 -> bf16 casts for all 5 inputs (one launch) ------------
__global__ void cast_all(const float* __restrict__ x, const float* __restrict__ mb,
                         const float* __restrict__ Wq, const float* __restrict__ Wk,
                         const float* __restrict__ Wv,
                         unsigned short* __restrict__ xb, unsigned short* __restrict__ mbb,
                         unsigned short* __restrict__ Wqb, unsigned short* __restrict__ Wkb,
                         unsigned short* __restrict__ Wvb, float* __restrict__ out_x) {
  int i = blockIdx.x * blockDim.x + threadIdx.x;  // float4 units
  const int NX = B_ * D_ / 4;    // 786432
  const int NMB = F_ * D_ / 4;   // 3145728
  const int NW = M_ * D_ / 4;    // 49152
  const int NWV = D_ * D_ / 4;   // 147456
  const float* src;
  unsigned short* dst;
  float* cpy = nullptr;
  int off;
  if (i < NX) { src = x; dst = xb; off = i; cpy = out_x; }
  else if ((i -= NX) < NMB) { src = mb; dst = mbb; off = i; }
  else if ((i -= NMB) < NW) { src = Wq; dst = Wqb; off = i; }
  else if ((i -= NW) < NW) { src = Wk; dst = Wkb; off = i; }
  else if ((i -= NW) < NWV) { src = Wv; dst = Wvb; off = i; }
  else return;
  float4 v = reinterpret_cast<const float4*>(src)[off];
  ushort4 u;
  u.x = f2bf(v.x); u.y = f2bf(v.y); u.z = f2bf(v.z); u.w = f2bf(v.w);
  reinterpret_cast<ushort4*>(dst)[off] = u;
  if (cpy) reinterpret_cast<float4*>(cpy)[off] = v;
}
#define CAST_UNITS (B_ * D_ / 4 + F_ * D_ / 4 + 2 * (M_ * D_ / 4) + D_ * D_ / 4)

// ---------------- merged Q/K/V projection GEMM (one launch, 1088 blocks) -----------
// Role by blockIdx.x: [0,64) Q = xb@Wqb^T+bq -> Qb (bf16);
//                     [64,320) K = mbb@Wkb^T+bk -> Kb (bf16);
//                     [320,1088) V = mbb@Wvb^T+bv -> out_V (f32).
// Loop body identical to gemm_bt (proven); runtime epi selects the trivial store.
__global__ __launch_bounds__(256, 2) void qkv_gemm(
    const unsigned short* __restrict__ xb, const unsigned short* __restrict__ mbb,
    const unsigned short* __restrict__ Wqb, const unsigned short* __restrict__ Wkb,
    const unsigned short* __restrict__ Wvb,
    const float* __restrict__ bq, const float* __restrict__ bk,
    const float* __restrict__ bv,
    unsigned short* __restrict__ Qb, unsigned short* __restrict__ Kb,
    float* __restrict__ out_V) {
  __shared__ unsigned short As[128 * 32];
  __shared__ unsigned short Bs[128 * 32];
  const int tid = threadIdx.x, lane = tid & 63, wave = tid >> 6;
  int bid = blockIdx.x;
  const unsigned short* A;
  const unsigned short* Bm;
  const float* bias;
  unsigned short* Cb = nullptr;
  float* Cf = nullptr;
  int m0, n0, N, epi;
  const int K = 768;
  if (bid < 64) {
    A = xb; Bm = Wqb; bias = bq; Cb = Qb; N = 256; epi = 0;
    n0 = (bid & 1) * 128; m0 = (bid >> 1) * 128;
  } else if (bid < 320) {
    bid -= 64;
    A = mbb; Bm = Wkb; bias = bk; Cb = Kb; N = 256; epi = 0;
    n0 = (bid & 1) * 128; m0 = (bid >> 1) * 128;
  } else {
    bid -= 320;
    A = mbb; Bm = Wvb; bias = bv; Cf = out_V; N = 768; epi = 1;
    n0 = (bid % 6) * 128; m0 = (bid / 6) * 128;
  }
  const int wr = wave >> 1, wc = wave & 1;
  const int q = lane >> 4;
  f32x4 acc[4][4] = {};

  for (int k0 = 0; k0 < K; k0 += 32) {
#pragma unroll
    for (int i = 0; i < 2; ++i) {
      int cb = (i * 4 + wave) * 64;
      int ch = cb + lane;
      int row = ch >> 2, ko = (ch & 3) * 8;
      gl_lds16(A + (size_t)(m0 + row) * K + k0 + ko, (char*)As + (size_t)cb * 16);
      gl_lds16(Bm + (size_t)(n0 + row) * K + k0 + ko, (char*)Bs + (size_t)cb * 16);
    }
    __syncthreads();
    bf16x8 a[4];
#pragma unroll
    for (int m = 0; m < 4; ++m)
      a[m] = *reinterpret_cast<const bf16x8*>(
          &As[(wr * 64 + m * 16 + (lane & 15)) * 32 + q * 8]);
#pragma unroll
    for (int n = 0; n < 4; ++n) {
      bf16x8 b = *reinterpret_cast<const bf16x8*>(
          &Bs[(wc * 64 + n * 16 + (lane & 15)) * 32 + q * 8]);
#pragma unroll
      for (int m = 0; m < 4; ++m)
        acc[m][n] = __builtin_amdgcn_mfma_f32_16x16x32_bf16(a[m], b, acc[m][n], 0, 0, 0);
    }
    __syncthreads();
  }

  const int rbase = m0 + wr * 64 + q * 4;
  const int cbase = n0 + wc * 64 + (lane & 15);
#pragma unroll
  for (int m = 0; m < 4; ++m) {
#pragma unroll
    for (int n = 0; n < 4; ++n) {
      int col = cbase + n * 16;
      float bvv = bias[col];
#pragma unroll
      for (int r = 0; r < 4; ++r) {
        float v = acc[m][n][r] + bvv;
        size_t idx = (size_t)(rbase + m * 16 + r) * N + col;
        if (epi == 0) Cb[idx] = f2bf(v);
        else Cf[idx] = v;
      }
    }
  }
}

// ---------------- gemm_bt: C[M,N] = A[M,K] * B[N,K]^T  (both bf16 K-contiguous) ----
// EPI 0: store bf16 (+bias)   EPI 1: store f32 (+bias)
// EPI 2: exp(c/temp) -> f32 E + rowsum      (fallback path)
// EPI 3: exp(c/temp) -> bf16 TILED E via LDS restage (coalesced ushort8) + rowsum
template <int EPI>
__global__ __launch_bounds__(256, 2) void gemm_bt(
    const unsigned short* __restrict__ A, const unsigned short* __restrict__ Bm,
    const float* __restrict__ bias, float* __restrict__ Cf,
    unsigned short* __restrict__ Cb, int M, int N, int K,
    float* __restrict__ rowsum, const float* __restrict__ tptr) {
  __shared__ unsigned short As[128 * 32];
  __shared__ unsigned short Bs[128 * 32];
  const int tid = threadIdx.x, lane = tid & 63, wave = tid >> 6;
  const int m0 = blockIdx.y * 128, n0 = blockIdx.x * 128;
  const int wr = wave >> 1, wc = wave & 1;
  const int q = lane >> 4;
  f32x4 acc[4][4] = {};

  for (int k0 = 0; k0 < K; k0 += 32) {
#pragma unroll
    for (int i = 0; i < 2; ++i) {
      int cb = (i * 4 + wave) * 64;
      int ch = cb + lane;
      int row = ch >> 2, ko = (ch & 3) * 8;
      gl_lds16(A + (size_t)(m0 + row) * K + k0 + ko, (char*)As + (size_t)cb * 16);
      gl_lds16(Bm + (size_t)(n0 + row) * K + k0 + ko, (char*)Bs + (size_t)cb * 16);
    }
    __syncthreads();
    bf16x8 a[4];
#pragma unroll
    for (int m = 0; m < 4; ++m)
      a[m] = *reinterpret_cast<const bf16x8*>(
          &As[(wr * 64 + m * 16 + (lane & 15)) * 32 + q * 8]);
#pragma unroll
    for (int n = 0; n < 4; ++n) {
      bf16x8 b = *reinterpret_cast<const bf16x8*>(
          &Bs[(wc * 64 + n * 16 + (lane & 15)) * 32 + q * 8]);
#pragma unroll
      for (int m = 0; m < 4; ++m)
        acc[m][n] = __builtin_amdgcn_mfma_f32_16x16x32_bf16(a[m], b, acc[m][n], 0, 0, 0);
    }
    __syncthreads();
  }

  const int rbase = m0 + wr * 64 + q * 4;
  const int cbase = n0 + wc * 64 + (lane & 15);
  if constexpr (EPI == 3) {
    __shared__ unsigned short Cs[128 * 128];   // 32 KB restage tile
    const float invt = 1.0f / tptr[0];
    const int rl0 = wr * 64 + q * 4, cl0 = wc * 64 + (lane & 15);
#pragma unroll
    for (int m = 0; m < 4; ++m) {
      float rs[4] = {0.f, 0.f, 0.f, 0.f};
#pragma unroll
      for (int n = 0; n < 4; ++n) {
#pragma unroll
        for (int r = 0; r < 4; ++r) {
          float e = __expf(acc[m][n][r] * invt);
          rs[r] += e;
          Cs[(rl0 + m * 16 + r) * 128 + cl0 + n * 16] = f2bf(e);
        }
      }
#pragma unroll
      for (int r = 0; r < 4; ++r) {
        float s = rs[r];
        s += __shfl_xor(s, 1);
        s += __shfl_xor(s, 2);
        s += __shfl_xor(s, 4);
        s += __shfl_xor(s, 8);
        if ((lane & 15) == 0) atomicAdd(&rowsum[rbase + m * 16 + r], s);
      }
    }
    __syncthreads();
    // coalesced tiled-E writeout: 2048 ushort8 units, 8 per thread
    const size_t ebase = ((size_t)(m0 >> 7) * 512 + (n0 >> 5)) * 4096;
#pragma unroll
    for (int j = 0; j < 8; ++j) {
      int u = j * 256 + tid;
      int tl = u >> 9, r = (u >> 2) & 127, p = u & 3;
      ushort8 v = *reinterpret_cast<const ushort8*>(
          &Cs[r * 128 + tl * 32 + ((p ^ ((r >> 1) & 3)) * 8)]);
      *reinterpret_cast<ushort8*>(&Cb[ebase + (size_t)tl * 4096 + r * 32 + p * 8]) = v;
    }
  } else if constexpr (EPI == 2) {
    const float invt = 1.0f / tptr[0];
#pragma unroll
    for (int m = 0; m < 4; ++m) {
      float rs[4] = {0.f, 0.f, 0.f, 0.f};
#pragma unroll
      for (int n = 0; n < 4; ++n) {
        int col = cbase + n * 16;
#pragma unroll
        for (int r = 0; r < 4; ++r) {
          float e = __expf(acc[m][n][r] * invt);
          Cf[(size_t)(rbase + m * 16 + r) * N + col] = e;
          rs[r] += e;
        }
      }
#pragma unroll
      for (int r = 0; r < 4; ++r) {
        float s = rs[r];
        s += __shfl_xor(s, 1);
        s += __shfl_xor(s, 2);
        s += __shfl_xor(s, 4);
        s += __shfl_xor(s, 8);
        if ((lane & 15) == 0) atomicAdd(&rowsum[rbase + m * 16 + r], s);
      }
    }
  } else {
#pragma unroll
    for (int m = 0; m < 4; ++m) {
#pragma unroll
      for (int n = 0; n < 4; ++n) {
        int col = cbase + n * 16;
        float bv = bias[col];
#pragma unroll
        for (int r = 0; r < 4; ++r) {
          float v = acc[m][n][r] + bv;
          size_t idx = (size_t)(rbase + m * 16 + r) * N + col;
          if (EPI == 0) Cb[idx] = f2bf(v);
          else Cf[idx] = v;
        }
      }
    }
  }
}

// ---------------- V[16384,768] f32 -> Vt_tiled bf16 --------------------------------
// Tile t: 48KB contiguous; xhat LDS image with XOR slot-swizzle pre-applied:
//   Vt_tiled[t*24576 + d*32 + s*8 + o] = bf16( V[t*32 + (s^((d>>1)&3))*8 + o][d] )
__global__ __launch_bounds__(256) void vt_tiler(const float* __restrict__ V,
                                                unsigned short* __restrict__ Vt_tiled) {
  __shared__ unsigned short T[768][36];
  const int t = blockIdx.x, k0 = t * 32, tid = threadIdx.x;
  const int kl = tid >> 3, c0 = (tid & 7) * 4;
  for (int cb = 0; cb < 768; cb += 32) {
    float4 v = *reinterpret_cast<const float4*>(&V[(size_t)(k0 + kl) * D_ + cb + c0]);
    T[cb + c0 + 0][kl] = f2bf(v.x);
    T[cb + c0 + 1][kl] = f2bf(v.y);
    T[cb + c0 + 2][kl] = f2bf(v.z);
    T[cb + c0 + 3][kl] = f2bf(v.w);
  }
  __syncthreads();
  for (int d = tid; d < 768; d += 256) {
    const int x = (d >> 1) & 3;
    unsigned short* o = Vt_tiled + (size_t)t * 24576 + d * 32;
#pragma unroll
    for (int s = 0; s < 4; ++s) {
      ushort4 lo = *reinterpret_cast<const ushort4*>(&T[d][(s ^ x) * 8]);
      ushort4 hi = *reinterpret_cast<const ushort4*>(&T[d][(s ^ x) * 8 + 4]);
      *reinterpret_cast<ushort4*>(o + s * 8) = lo;
      *reinterpret_cast<ushort4*>(o + s * 8 + 4) = hi;
    }
  }
}

// ---------------- xhat (round-8/12 proven): 512-thr 8-wave, BK=64, KS=4 ------------
// partial[ks][128x192 tile] = (E_chunk @ V_chunk) * diag(1/rowsum), bf16.
// Wave grid 2x4, wave tile 64x48, acc[4][3]. Waves 0-3 stage A (4 chunks each = 16),
// waves 4-7 stage B (6 chunks each = 24 = 192rows x 64k). 64 steps, 48 MFMA/wave.
// combo = bid&15 (ks=combo>>2, nb=combo&3), mb = bid>>4 -> same-combo blocks share
// an XCD (%8 round-robin): 2 V-panels x 1.5MB = 3MB < 4MB L2.
__global__ __launch_bounds__(512, 4) void xhat_clean(
    const unsigned short* __restrict__ Et, const unsigned short* __restrict__ Vtt,
    const float* __restrict__ rowsum, unsigned short* __restrict__ partial) {
  __shared__ unsigned short As[2][128 * 32];   // 16 KB
  __shared__ unsigned short Bs[2][192 * 32];   // 24 KB
  const int tid = threadIdx.x, lane = tid & 63, wave = tid >> 6;
  const int combo = blockIdx.x & 15, mb = blockIdx.x >> 4;
  const int ks = combo >> 2, nb = combo & 3;
  const int q = lane >> 4;
  const int wr = wave >> 2, wc = wave & 3;  // wave tile 64r x 48c
  const int t0 = ks * 128;
  f32x4 acc[4][3] = {};

  const unsigned short* abase =
      Et + ((size_t)mb * 512 + t0) * 4096 + lane * 8;
  const unsigned short* bbase =
      Vtt + (size_t)t0 * 24576 + nb * 6144 + lane * 8;

  for (int si = 0; si < 64; ++si) {
    const size_t tA = (size_t)(2 * si) * 4096;
    const size_t tB = (size_t)(2 * si) * 24576;
    if (wave < 4) {
      // A: 128r x 64k = 16 chunks of 512 shorts; 4 per wave
#pragma unroll
      for (int j = 0; j < 4; ++j) {
        int c = wave * 4 + j;         // 0..15
        int h = c >> 3, cw = c & 7;
        gl_lds16(abase + tA + (size_t)h * 4096 + cw * 512,
                 (char*)As + h * 8192 + cw * 1024);
      }
    } else {
      // B: 192r x 64k = 24 chunks of 512 shorts; 6 per wave
#pragma unroll
      for (int j = 0; j < 6; ++j) {
        int c = (wave - 4) * 6 + j;   // 0..23
        int h = c / 12, cc = c % 12;
        gl_lds16(bbase + tB + (size_t)h * 24576 + cc * 512,
                 (char*)Bs + h * 12288 + cc * 1024);
      }
    }
    __syncthreads();
#pragma unroll
    for (int h = 0; h < 2; ++h) {
      bf16x8 a[4], b[3];
#pragma unroll
      for (int m = 0; m < 4; ++m) {
        int R = wr * 64 + m * 16 + (lane & 15);
        a[m] = *reinterpret_cast<const bf16x8*>(
            &As[h][R * 32 + ((q ^ ((R >> 1) & 3)) * 8)]);
      }
#pragma unroll
      for (int n = 0; n < 3; ++n) {
        int C = wc * 48 + n * 16 + (lane & 15);
        b[n] = *reinterpret_cast<const bf16x8*>(
            &Bs[h][C * 32 + ((q ^ ((C >> 1) & 3)) * 8)]);
      }
#pragma unroll
      for (int n = 0; n < 3; ++n)
#pragma unroll
        for (int m = 0; m < 4; ++m)
          acc[m][n] = __builtin_amdgcn_mfma_f32_16x16x32_bf16(a[m], b[n], acc[m][n], 0, 0, 0);
    }
    __syncthreads();
  }

  unsigned short* P = partial + (size_t)ks * B_ * D_;
#pragma unroll
  for (int m = 0; m < 4; ++m) {
    int rowb = mb * 128 + wr * 64 + m * 16 + q * 4;
#pragma unroll
    for (int r = 0; r < 4; ++r) {
      float inv = 1.0f / rowsum[rowb + r];
      size_t ro = (size_t)(rowb + r) * D_;
#pragma unroll
      for (int n = 0; n < 3; ++n) {
        int col = nb * 192 + wc * 48 + n * 16 + (lane & 15);
        P[ro + col] = f2bf(acc[m][n][r] * inv);
      }
    }
  }
}

// ---------------- fused tail: x_hat reduce (nks=4) + f normalize in one launch -----
__global__ __launch_bounds__(256) void norm_reduce(
    const unsigned short* __restrict__ partial, float* __restrict__ out_xhat,
    const unsigned short* __restrict__ Et, const float* __restrict__ rowsum,
    float* __restrict__ f) {
  const int NRED = B_ * D_ / 8;  // 393216
  int i = blockIdx.x * blockDim.x + threadIdx.x;
  if (i < NRED) {
    size_t base = (size_t)i * 8;
    float s[8] = {0.f, 0.f, 0.f, 0.f, 0.f, 0.f, 0.f, 0.f};
#pragma unroll
    for (int ks = 0; ks < 4; ++ks) {
      ushort8 v = *reinterpret_cast<const ushort8*>(&partial[(size_t)ks * B_ * D_ + base]);
#pragma unroll
      for (int j = 0; j < 8; ++j) s[j] += bf2f(v[j]);
    }
    float4 o0 = make_float4(s[0], s[1], s[2], s[3]);
    float4 o1 = make_float4(s[4], s[5], s[6], s[7]);
    *reinterpret_cast<float4*>(&out_xhat[base]) = o0;
    *reinterpret_cast<float4*>(&out_xhat[base + 4]) = o1;
    return;
  }
  int u = i - NRED;
  if (u >= B_ * F_ / 8) return;
  int g = u >> 9, w = u & 511;                    // 512 units per 128x32 tile
  int r = w >> 2, p = w & 3;
  int rb = g >> 9, t = g & 511;
  int row = rb * 128 + r;
  int col = t * 32 + (p ^ ((r >> 1) & 3)) * 8;
  float inv = 1.0f / rowsum[row];
  ushort8 e = *reinterpret_cast<const ushort8*>(&Et[(size_t)g * 4096 + w * 8]);
  float4 o0, o1;
  o0.x = bf2f(e[0]) * inv; o0.y = bf2f(e[1]) * inv;
  o0.z = bf2f(e[2]) * inv; o0.w = bf2f(e[3]) * inv;
  o1.x = bf2f(e[4]) * inv; o1.y = bf2f(e[5]) * inv;
  o1.z = bf2f(e[6]) * inv; o1.w = bf2f(e[7]) * inv;
  float* fp = &f[(size_t)row * F_ + col];
  *reinterpret_cast<float4*>(fp) = o0;
  *reinterpret_cast<float4*>(fp + 4) = o1;
}

// ---------------- xhat v4 (fallback, round-4 proven) -------------------------------
__global__ __launch_bounds__(512, 4) void xhat_v4(
    float* __restrict__ Ef, const unsigned short* __restrict__ Vt_tiled,
    const float* __restrict__ rowsum, unsigned short* __restrict__ partial) {
  __shared__ unsigned short As2[64 * 32];
  __shared__ unsigned short Vs[768 * 32];
  const int tid = threadIdx.x, lane = tid & 63, wave = tid >> 6;
  const int ks = blockIdx.x & 7, rb = blockIdx.x >> 3;
  const int r0 = rb * 64;
  const int kbeg = ks * (F_ / 8);
  const int wr = wave >> 2, wc = wave & 3;
  const int erow = tid >> 3, ec = (tid & 7) * 4;
  const float inv_f = 1.0f / rowsum[r0 + erow];
  const int q = lane >> 4;
  f32x4 acc[2][12] = {};

  float* ep = Ef + (size_t)(r0 + erow) * F_ + kbeg + ec;
  float4 e = *reinterpret_cast<const float4*>(ep);
  const int NSTEP = (F_ / 8) / 32;
  const unsigned short* vt_base =
      Vt_tiled + (size_t)(kbeg >> 5) * 24576 + wave * 512 + lane * 8;

  for (int si = 0; si < NSTEP; ++si) {
    float4 f4 = make_float4(e.x * inv_f, e.y * inv_f, e.z * inv_f, e.w * inv_f);
    *reinterpret_cast<float4*>(ep) = f4;
    ushort4 u;
    u.x = f2bf(e.x); u.y = f2bf(e.y); u.z = f2bf(e.z); u.w = f2bf(e.w);
    {
      int slot = ec >> 3, off = ec & 7;
      *reinterpret_cast<ushort4*>(
          &As2[erow * 32 + ((slot ^ ((erow >> 1) & 3)) * 8) + off]) = u;
    }
    const unsigned short* vs_src = vt_base + (size_t)si * 24576;
#pragma unroll
    for (int j = 0; j < 6; ++j)
      gl_lds16(vs_src + j * 4096, (char*)Vs + (size_t)(j * 512 + wave * 64) * 16);
    __syncthreads();
    if (si + 1 < NSTEP) e = *reinterpret_cast<const float4*>(ep + 32);
    ep += 32;
    bf16x8 a[2];
#pragma unroll
    for (int m = 0; m < 2; ++m) {
      int R = wr * 32 + m * 16 + (lane & 15);
      a[m] = *reinterpret_cast<const bf16x8*>(&As2[R * 32 + ((q ^ ((R >> 1) & 3)) * 8)]);
    }
#pragma unroll
    for (int n = 0; n < 12; ++n) {
      int C = wc * 192 + n * 16 + (lane & 15);
      bf16x8 b = *reinterpret_cast<const bf16x8*>(&Vs[C * 32 + ((q ^ ((C >> 1) & 3)) * 8)]);
      acc[0][n] = __builtin_amdgcn_mfma_f32_16x16x32_bf16(a[0], b, acc[0][n], 0, 0, 0);
      acc[1][n] = __builtin_amdgcn_mfma_f32_16x16x32_bf16(a[1], b, acc[1][n], 0, 0, 0);
    }
    __syncthreads();
  }

  unsigned short* P = partial + (size_t)ks * B_ * D_;
#pragma unroll
  for (int m = 0; m < 2; ++m) {
    int rowb = r0 + wr * 32 + m * 16 + q * 4;
#pragma unroll
    for (int r = 0; r < 4; ++r) {
      float inv = 1.0f / rowsum[rowb + r];
      size_t row_off = (size_t)(rowb + r) * D_;
#pragma unroll
      for (int n = 0; n < 12; ++n) {
        int col = wc * 192 + n * 16 + (lane & 15);
        P[row_off + col] = f2bf(acc[m][n][r] * inv);
      }
    }
  }
}

// ---------------- sum nks bf16 partials -> f32 x_hat (fallback path) ---------------
__global__ void reduce_kernel(const unsigned short* __restrict__ partial,
                              float* __restrict__ out, int n8, int nks) {
  int i = blockIdx.x * blockDim.x + threadIdx.x;
  if (i >= n8) return;
  size_t base = (size_t)i * 8;
  float s[8] = {0.f, 0.f, 0.f, 0.f, 0.f, 0.f, 0.f, 0.f};
  for (int ks = 0; ks < nks; ++ks) {
    ushort8 v = *reinterpret_cast<const ushort8*>(&partial[(size_t)ks * B_ * D_ + base]);
#pragma unroll
    for (int j = 0; j < 8; ++j) s[j] += bf2f(v[j]);
  }
  float4 o0 = make_float4(s[0], s[1], s[2], s[3]);
  float4 o1 = make_float4(s[4], s[5], s[6], s[7]);
  *reinterpret_cast<float4*>(&out[base]) = o0;
  *reinterpret_cast<float4*>(&out[base + 4]) = o1;
}

extern "C" void kernel_launch(void* const* d_in, const int* in_sizes, int n_in,
                              void* d_out, int out_size, void* d_ws, size_t ws_size,
                              hipStream_t stream) {
  const float* x = (const float*)d_in[0];
  const float* mb = (const float*)d_in[1];
  const float* Wq = (const float*)d_in[2];
  const float* bq = (const float*)d_in[3];
  const float* Wk = (const float*)d_in[4];
  const float* bk = (const float*)d_in[5];
  const float* Wv = (const float*)d_in[6];
  const float* bv = (const float*)d_in[7];
  const float* temp = (const float*)d_in[8];

  float* out_x = (float*)d_out;
  float* out_xhat = out_x + (size_t)B_ * D_;
  float* out_f = out_xhat + (size_t)B_ * D_;
  float* out_V = out_f + (size_t)B_ * F_;

  char* ws = (char*)d_ws;
  const size_t WS_NEED_NEW = 195051520;  // new-path peak usage

  if (ws_size >= WS_NEED_NEW) {
    // ---------- r15 proven path + merged QKV projection launch ----------
    unsigned short* Qb  = (unsigned short*)(ws + 0);          // 2097152
    unsigned short* Kb  = (unsigned short*)(ws + 2097152);    // 8388608
    unsigned short* Vtt = (unsigned short*)(ws + 10485760);   // 25165824
    float* rowsum       = (float*)(ws + 35651584);            // 16384
    char* A0 = ws + 35667968;                                 // cast area / E_tiled
    unsigned short* xb  = (unsigned short*)(A0 + 0);          // 6291456
    unsigned short* mbb = (unsigned short*)(A0 + 6291456);    // 25165824
    unsigned short* Wqb = (unsigned short*)(A0 + 31457280);   // 393216
    unsigned short* Wkb = (unsigned short*)(A0 + 31850496);   // 393216
    unsigned short* Wvb = (unsigned short*)(A0 + 32243712);   // 1179648
    unsigned short* Et  = (unsigned short*)A0;                // 134217728 (overlays casts)
    unsigned short* partial = (unsigned short*)(ws + 169885696); // 4*6291456 = 25165824

    hipMemsetAsync(rowsum, 0, B_ * sizeof(float), stream);

    cast_all<<<(CAST_UNITS + 255) / 256, 256, 0, stream>>>(x, mb, Wq, Wk, Wv, xb, mbb,
                                                           Wqb, Wkb, Wvb, out_x);

    // merged Q/K/V projections (one launch, 1088 blocks)
    qkv_gemm<<<dim3(1088), dim3(256), 0, stream>>>(xb, mbb, Wqb, Wkb, Wvb, bq, bk, bv,
                                                   Qb, Kb, out_V);
    vt_tiler<<<dim3(F_ / 32), 256, 0, stream>>>(out_V, Vtt);
    // E (bf16 tiled, overlays dead cast buffers) + rowsum
    gemm_bt<3><<<dim3(F_ / 128, B_ / 128), dim3(256), 0, stream>>>(
        Qb, Kb, nullptr, nullptr, Et, B_, F_, M_, rowsum, temp);
    // xhat immediately after scores (Et hottest in L2/L3)
    xhat_clean<<<dim3(512), dim3(512), 0, stream>>>(Et, Vtt, rowsum, partial);
    // fused tail: x_hat reduce + f normalize
    const int NTAIL = B_ * D_ / 8 + B_ * F_ / 8;
    norm_reduce<<<(NTAIL + 255) / 256, 256, 0, stream>>>(partial, out_xhat, Et, rowsum,
                                                         out_f);
  } else {
    // ---------- fallback: round-4 proven pipeline ----------
    unsigned short* xb  = (unsigned short*)(ws + 0);
    unsigned short* mbb = (unsigned short*)(ws + 6291456);
    unsigned short* Wqb = (unsigned short*)(ws + 31457280);
    unsigned short* Wkb = (unsigned short*)(ws + 31850496);
    unsigned short* Wvb = (unsigned short*)(ws + 32243712);
    unsigned short* Qb  = (unsigned short*)(ws + 33423360);
    unsigned short* Kb  = (unsigned short*)(ws + 35520512);
    unsigned short* Vtt = (unsigned short*)(ws + 43909120);
    float* rowsum       = (float*)(ws + 69074944);
    unsigned short* partial = (unsigned short*)(ws + 69091328);

    hipMemsetAsync(rowsum, 0, B_ * sizeof(float), stream);

    cast_all<<<(CAST_UNITS + 255) / 256, 256, 0, stream>>>(x, mb, Wq, Wk, Wv, xb, mbb,
                                                           Wqb, Wkb, Wvb, out_x);

    dim3 blk(256);
    gemm_bt<0><<<dim3(M_ / 128, B_ / 128), blk, 0, stream>>>(xb, Wqb, bq, nullptr, Qb,
                                                             B_, M_, D_, nullptr, nullptr);
    gemm_bt<0><<<dim3(M_ / 128, F_ / 128), blk, 0, stream>>>(mbb, Wkb, bk, nullptr, Kb,
                                                             F_, M_, D_, nullptr, nullptr);
    gemm_bt<1><<<dim3(D_ / 128, F_ / 128), blk, 0, stream>>>(mbb, Wvb, bv, out_V, nullptr,
                                                             F_, D_, D_, nullptr, nullptr);
    vt_tiler<<<dim3(F_ / 32), 256, 0, stream>>>(out_V, Vtt);
    gemm_bt<2><<<dim3(F_ / 128, B_ / 128), blk, 0, stream>>>(Qb, Kb, nullptr, out_f, nullptr,
                                                             B_, F_, M_, rowsum, temp);
    xhat_v4<<<dim3(512), dim3(512), 0, stream>>>(out_f, Vtt, rowsum, partial);
    reduce_kernel<<<(B_ * D_ / 8 + 255) / 256, 256, 0, stream>>>(partial, out_xhat,
                                                                 B_ * D_ / 8, 8);
  }
}